// Round 1
// baseline (2470.415 us; speedup 1.0000x reference)
//
#include <hip/hip_runtime.h>
#include <hip/hip_bf16.h>

#define H1 57   // 64-8+1
#define H2 53   // 57-5+1

// ---------------- conv1: 3->16, 8x8, VALID, relu, out bf16 ----------------
// grid (512 imgs, 15 row-groups of 4), block 256.
// lane: ry = lane>>4 (0..3), xg = lane&15 (x0 = 4*xg, active xg<15)
// wave-uniform oc task loop; weights read via wave-uniform (scalar) loads.
__global__ __launch_bounds__(256) void k_conv1(const float* __restrict__ in,
    const float* __restrict__ w1, const float* __restrict__ b1,
    __hip_bfloat16* __restrict__ out1)
{
  __shared__ float sIn[3][11][72];
  const int img = blockIdx.x;
  const int y0 = blockIdx.y * 4;
  const int reff = min(4, H1 - y0);
  const int nrows = reff + 7;            // <= 11
  for (int idx = threadIdx.x; idx < 3 * nrows * 64; idx += 256) {
    int x = idx & 63;
    int t = idx >> 6;
    int r = t % nrows;
    int c = t / nrows;
    sIn[c][r][x] = in[((img * 3 + c) * 64 + (y0 + r)) * 64 + x];
  }
  __syncthreads();
  const int lane = threadIdx.x & 63;
  const int wv = __builtin_amdgcn_readfirstlane(threadIdx.x >> 6);
  const int ry = lane >> 4;
  const int xg = lane & 15;
  const int x0 = xg * 4;
  const bool rowok = (ry < reff);
  for (int t = wv; t < 16; t += 4) {
    const int oc = t;
    float acc[4] = {0.f, 0.f, 0.f, 0.f};
    for (int c = 0; c < 3; ++c) {
      #pragma unroll
      for (int kh = 0; kh < 8; ++kh) {
        const float* row = &sIn[c][ry + kh][x0];
        float4 i0 = *(const float4*)(row);
        float4 i1 = *(const float4*)(row + 4);
        float4 i2 = *(const float4*)(row + 8);
        float xv[12] = {i0.x, i0.y, i0.z, i0.w, i1.x, i1.y, i1.z, i1.w,
                        i2.x, i2.y, i2.z, i2.w};
        const float* wr = &w1[((oc * 3 + c) * 8 + kh) * 8];
        #pragma unroll
        for (int kw = 0; kw < 8; ++kw) {
          float wt = wr[kw];
          #pragma unroll
          for (int i = 0; i < 4; ++i)
            acc[i] = fmaf(xv[kw + i], wt, acc[i]);
        }
      }
    }
    if (rowok) {
      const float bias = b1[oc];
      const int yy = y0 + ry;
      #pragma unroll
      for (int i = 0; i < 4; ++i) {
        int xx = x0 + i;
        if (xx < H1)
          out1[((img * 16 + oc) * H1 + yy) * H1 + xx] =
              __float2bfloat16(fmaxf(acc[i] + bias, 0.f));
      }
    }
  }
}

// ---------------- conv2: 16->32, 5x5, VALID, relu, fused global max ----------------
// grid (512 imgs, 14 row-groups of 4), block 256.
// lane: ry = lane>>4 (0..3), xg = lane&15 (active xg<14), 2 oc per task.
__global__ __launch_bounds__(256) void k_conv2(const __hip_bfloat16* __restrict__ in1,
    const float* __restrict__ w2, const float* __restrict__ b2,
    float* __restrict__ feat)
{
  __shared__ float sIn[16][8][68];
  __shared__ unsigned smax[32];
  const int img = blockIdx.x;
  const int y0 = blockIdx.y * 4;
  const int reff = min(4, H2 - y0);
  const int nrows = reff + 4;            // <= 8
  if (threadIdx.x < 32) smax[threadIdx.x] = 0u;
  for (int idx = threadIdx.x; idx < 16 * nrows * H1; idx += 256) {
    int x = idx % H1;
    int t = idx / H1;
    int r = t % nrows;
    int c = t / nrows;
    sIn[c][r][x] = __bfloat162float(in1[((img * 16 + c) * H1 + (y0 + r)) * H1 + x]);
  }
  __syncthreads();
  const int lane = threadIdx.x & 63;
  const int wv = __builtin_amdgcn_readfirstlane(threadIdx.x >> 6);
  const int ry = lane >> 4;
  const int xg = lane & 15;
  const int x0 = xg * 4;
  const bool rowok = (ry < reff) && (xg < 14);
  for (int t = wv; t < 16; t += 4) {
    const int oc0 = t * 2;
    float acc0[4] = {0.f, 0.f, 0.f, 0.f};
    float acc1[4] = {0.f, 0.f, 0.f, 0.f};
    for (int c = 0; c < 16; ++c) {
      #pragma unroll
      for (int kh = 0; kh < 5; ++kh) {
        const float* row = &sIn[c][ry + kh][x0];
        float4 i0 = *(const float4*)(row);
        float4 i1 = *(const float4*)(row + 4);
        float xv[8] = {i0.x, i0.y, i0.z, i0.w, i1.x, i1.y, i1.z, i1.w};
        const float* wr0 = &w2[((oc0 * 16 + c) * 5 + kh) * 5];
        const float* wr1 = wr0 + 400;   // next oc: 16*5*5
        #pragma unroll
        for (int kw = 0; kw < 5; ++kw) {
          float wa = wr0[kw];
          float wb = wr1[kw];
          #pragma unroll
          for (int i = 0; i < 4; ++i) {
            acc0[i] = fmaf(xv[kw + i], wa, acc0[i]);
            acc1[i] = fmaf(xv[kw + i], wb, acc1[i]);
          }
        }
      }
    }
    float m0 = 0.f, m1 = 0.f;
    if (rowok) {
      const float ba = b2[oc0], bb = b2[oc0 + 1];
      #pragma unroll
      for (int i = 0; i < 4; ++i) {
        if (x0 + i < H2) {
          m0 = fmaxf(m0, acc0[i] + ba);
          m1 = fmaxf(m1, acc1[i] + bb);
        }
      }
      m0 = fmaxf(m0, 0.f);   // relu (max of relu == relu of max)
      m1 = fmaxf(m1, 0.f);
    }
    #pragma unroll
    for (int d = 32; d >= 1; d >>= 1) {
      m0 = fmaxf(m0, __shfl_xor(m0, d, 64));
      m1 = fmaxf(m1, __shfl_xor(m1, d, 64));
    }
    if (lane == 0) {
      atomicMax(&smax[oc0], __float_as_uint(m0));
      atomicMax(&smax[oc0 + 1], __float_as_uint(m1));
    }
  }
  __syncthreads();
  if (threadIdx.x < 32)
    atomicMax((unsigned*)&feat[img * 32 + threadIdx.x], smax[threadIdx.x]);
}

// ---------------- head: adjacency + graph layer + MLP ----------------
// one block (256 thr) per batch element.
__global__ __launch_bounds__(256) void k_head(const float* __restrict__ diffs,
    const float* __restrict__ feat, const float* __restrict__ gw,
    const float* __restrict__ gb, const float* __restrict__ w4,
    const float* __restrict__ b4, const float* __restrict__ w5,
    const float* __restrict__ b5, float* __restrict__ out)
{
  __shared__ float h66[4][66];
  __shared__ float hout[4][512];
  __shared__ float Am[4][4];
  __shared__ float pd[4][4][2];
  __shared__ float fs[4][32];
  const int b = blockIdx.x;
  const int tid = threadIdx.x;
  if (tid < 128) {
    int i = tid >> 5, c = tid & 31;
    fs[i][c] = feat[(b * 4 + i) * 32 + c];
  }
  if (tid == 0) {
    float lx[4], ly[4];
    #pragma unroll
    for (int a = 0; a < 4; ++a) {
      lx[a] = diffs[(b * 4 + a) * 2];
      ly[a] = diffs[(b * 4 + a) * 2 + 1];
    }
    #pragma unroll
    for (int i = 0; i < 4; ++i) {
      float A[4];
      float rs = 0.f;
      #pragma unroll
      for (int j = 0; j < 4; ++j) {
        float dx = lx[i] - lx[j], dy = ly[i] - ly[j];
        pd[i][j][0] = dx;
        pd[i][j][1] = dy;
        float n = sqrtf(dx * dx + dy * dy);
        A[j] = (n < 1.41421356237309504880f) ? 1.f : 0.f;
        rs += A[j];
      }
      float inv = 1.f / fmaxf(rs, 1e-6f);   // clip(sum, 1e-6); diagonal counted
      #pragma unroll
      for (int j = 0; j < 4; ++j)
        Am[i][j] = (i == j) ? 0.f : A[j] * inv;   // mask AFTER normalize
    }
  }
  __syncthreads();
  if (tid < 128) {
    int i = tid >> 5, c = tid & 31;
    h66[i][c] = fs[i][c];
    float s = 0.f;
    #pragma unroll
    for (int j = 0; j < 4; ++j) s += Am[i][j] * fs[j][c];
    h66[i][32 + c] = s;
  } else if (tid < 136) {
    int q = tid - 128;
    int i = q >> 1, d = q & 1;
    float s = 0.f;
    #pragma unroll
    for (int j = 0; j < 4; ++j) s += Am[i][j] * pd[i][j][d];
    h66[i][64 + d] = s;
  }
  __syncthreads();
  #pragma unroll
  for (int r = 0; r < 2; ++r) {
    int o = tid + 256 * r;
    const float* wrow = &gw[o * 66];
    float a0 = gb[o], a1 = a0, a2 = a0, a3 = a0;
    for (int c = 0; c < 66; ++c) {
      float wv = wrow[c];
      a0 = fmaf(h66[0][c], wv, a0);
      a1 = fmaf(h66[1][c], wv, a1);
      a2 = fmaf(h66[2][c], wv, a2);
      a3 = fmaf(h66[3][c], wv, a3);
    }
    hout[0][o] = fmaxf(a0, 0.f);
    hout[1][o] = fmaxf(a1, 0.f);
    hout[2][o] = fmaxf(a2, 0.f);
    hout[3][o] = fmaxf(a3, 0.f);
  }
  __syncthreads();
  if (tid < 192) {
    int g = tid >> 4, l = tid & 15;
    int i = g / 3, k = g % 3;
    const float* wrow = (k < 2) ? &w4[k * 512] : w5;
    float s = 0.f;
    for (int o = l; o < 512; o += 16) s = fmaf(hout[i][o], wrow[o], s);
    #pragma unroll
    for (int d = 8; d >= 1; d >>= 1) s += __shfl_xor(s, d, 16);
    if (l == 0) {
      if (k < 2) out[(b * 4 + i) * 2 + k] = s + b4[k];
      else       out[1024 + b * 4 + i] = s + b5[0];
    }
  }
}

extern "C" void kernel_launch(void* const* d_in, const int* in_sizes, int n_in,
                              void* d_out, int out_size, void* d_ws, size_t ws_size,
                              hipStream_t stream) {
  const float* diffs  = (const float*)d_in[0];
  const float* states = (const float*)d_in[1];
  const float* w1 = (const float*)d_in[2];
  const float* b1 = (const float*)d_in[3];
  const float* w2 = (const float*)d_in[4];
  const float* b2 = (const float*)d_in[5];
  const float* gw = (const float*)d_in[6];
  const float* gb = (const float*)d_in[7];
  const float* w4 = (const float*)d_in[8];
  const float* b4 = (const float*)d_in[9];
  const float* w5 = (const float*)d_in[10];
  const float* b5 = (const float*)d_in[11];
  float* out = (float*)d_out;

  __hip_bfloat16* out1 = (__hip_bfloat16*)d_ws;                  // 512*16*57*57 bf16
  size_t out1_bytes = (size_t)512 * 16 * H1 * H1 * sizeof(__hip_bfloat16);
  float* feat = (float*)((char*)d_ws + ((out1_bytes + 255) & ~(size_t)255));

  hipMemsetAsync(feat, 0, 512 * 32 * sizeof(float), stream);     // atomicMax identity (+0.0f)
  k_conv1<<<dim3(512, 15), 256, 0, stream>>>(states, w1, b1, out1);
  k_conv2<<<dim3(512, 14), 256, 0, stream>>>(out1, w2, b2, feat);
  k_head<<<128, 256, 0, stream>>>(diffs, feat, gw, gb, w4, b4, w5, b5, out);
}

// Round 2
// 521.489 us; speedup vs baseline: 4.7372x; 4.7372x over previous
//
#include <hip/hip_runtime.h>
#include <hip/hip_bf16.h>

#define H1 57   // 64-8+1
#define H2 53   // 57-5+1

typedef _Float16 f16;
typedef _Float16 h2 __attribute__((ext_vector_type(2)));

#if __has_builtin(__builtin_amdgcn_fdot2)
#define FDOT2(a,b,c) __builtin_amdgcn_fdot2((a),(b),(c),false)
#else
#define FDOT2(a,b,c) fmaf((float)(a).y,(float)(b).y, fmaf((float)(a).x,(float)(b).x,(c)))
#endif

// ---------------- weight repack ----------------
// wt1[c][kh][kw][oc16] fp32 ; w2p[p][kh][kw][oc32] f16x2 (p = channel pair)
__global__ __launch_bounds__(256) void k_repack(const float* __restrict__ w1,
    const float* __restrict__ w2, float* __restrict__ wt1, h2* __restrict__ w2p)
{
  int t = threadIdx.x;
  for (int i = t; i < 3 * 8 * 8 * 16; i += 256) {
    int oc = i & 15;
    int r = i >> 4;                       // (c*8+kh)*8+kw
    wt1[i] = w1[oc * 192 + r];
  }
  for (int i = t; i < 8 * 5 * 5 * 32; i += 256) {
    int oc = i & 31;
    int r = i >> 5;                       // (p*5+kh)*5+kw
    int p = r / 25, rem = r % 25;
    float a = w2[oc * 400 + (2 * p) * 25 + rem];
    float b = w2[oc * 400 + (2 * p + 1) * 25 + rem];
    h2 v; v.x = (f16)a; v.y = (f16)b;
    w2p[i] = v;
  }
}

// ---------------- conv1: 3->16, 8x8, VALID, relu, out f16x2 pairs ----------------
// grid (512 imgs, 15 groups of 4 rows), block 256 = 4 waves, wave = one y row,
// lane = one x. Each lane accumulates all 16 oc in registers; weights via
// wave-uniform (scalar) loads from repacked wt1.
__global__ __launch_bounds__(256) void k_conv1(const float* __restrict__ in,
    const float* __restrict__ wt1, const float* __restrict__ b1,
    h2* __restrict__ out1)
{
  __shared__ float sIn[3][11][64];
  const int img = blockIdx.x;
  const int y0 = blockIdx.y * 4;
  const int reff = min(4, H1 - y0);
  for (int idx = threadIdx.x; idx < 3 * 11 * 64; idx += 256) {
    int x = idx & 63;
    int t = idx >> 6;
    int r = t % 11;
    int c = t / 11;
    int y = min(y0 + r, 63);              // clamp: rows beyond reff+6 never used
    sIn[c][r][x] = in[((img * 3 + c) * 64 + y) * 64 + x];
  }
  __syncthreads();
  const int w = __builtin_amdgcn_readfirstlane(threadIdx.x >> 6);
  const int lane = threadIdx.x & 63;
  const int x = min(lane, H1 - 1);
  float acc[16];
  #pragma unroll
  for (int o = 0; o < 16; ++o) acc[o] = b1[o];
  for (int c = 0; c < 3; ++c) {
    for (int kh = 0; kh < 8; ++kh) {
      const float* srow = &sIn[c][w + kh][0];
      const float* wp = &wt1[((c * 8 + kh) * 8) * 16];
      #pragma unroll
      for (int kw = 0; kw < 8; ++kw) {
        float xv = srow[x + kw];
        #pragma unroll
        for (int o = 0; o < 16; ++o)
          acc[o] = fmaf(xv, wp[kw * 16 + o], acc[o]);
      }
    }
  }
  if (w < reff && lane < H1) {
    const int y = y0 + w;
    #pragma unroll
    for (int p = 0; p < 8; ++p) {
      h2 v;
      v.x = (f16)fmaxf(acc[2 * p], 0.f);
      v.y = (f16)fmaxf(acc[2 * p + 1], 0.f);
      out1[((img * 8 + p) * H1 + y) * H1 + x] = v;
    }
  }
}

// ---------------- conv2: 16->32, 5x5, VALID, relu, fused global max ----------------
// grid (512 imgs, 14 groups of 4 rows), block 256 = 4 waves, wave = one y row,
// lane = one x. 32 oc accumulators per lane, v_dot2_f32_f16 over channel pairs.
__global__ __launch_bounds__(256) void k_conv2(const h2* __restrict__ in1,
    const h2* __restrict__ w2p, const float* __restrict__ b2,
    float* __restrict__ feat)
{
  __shared__ h2 sIn[8][8][60];
  __shared__ unsigned smax[32];
  const int img = blockIdx.x;
  const int y0 = blockIdx.y * 4;
  const int reff = min(4, H2 - y0);
  if (threadIdx.x < 32) smax[threadIdx.x] = 0u;
  for (int idx = threadIdx.x; idx < 8 * 8 * H1; idx += 256) {
    int x = idx % H1;
    int t = idx / H1;
    int r = t & 7;
    int p = t >> 3;
    int y = min(y0 + r, H1 - 1);          // clamp: rows beyond reff+3 never used
    sIn[p][r][x] = in1[((img * 8 + p) * H1 + y) * H1 + x];
  }
  __syncthreads();
  const int w = __builtin_amdgcn_readfirstlane(threadIdx.x >> 6);
  const int lane = threadIdx.x & 63;
  const int x = min(lane, H2 - 1);
  float acc[32];
  #pragma unroll
  for (int o = 0; o < 32; ++o) acc[o] = 0.f;
  for (int p = 0; p < 8; ++p) {
    for (int kh = 0; kh < 5; ++kh) {
      const h2* srow = &sIn[p][w + kh][0];
      const h2* wp = &w2p[((p * 5 + kh) * 5) * 32];
      #pragma unroll
      for (int kw = 0; kw < 5; ++kw) {
        h2 xv = srow[x + kw];
        #pragma unroll
        for (int o = 0; o < 32; ++o)
          acc[o] = FDOT2(xv, wp[kw * 32 + o], acc[o]);
      }
    }
  }
  const bool act = (w < reff);            // inactive waves/rows contribute 0
  #pragma unroll
  for (int o = 0; o < 32; ++o) {
    float v = act ? fmaxf(acc[o] + b2[o], 0.f) : 0.f;
    #pragma unroll
    for (int d = 32; d >= 1; d >>= 1)
      v = fmaxf(v, __shfl_xor(v, d, 64));
    if (lane == 0) atomicMax(&smax[o], __float_as_uint(v));
  }
  __syncthreads();
  if (threadIdx.x < 32)
    atomicMax((unsigned*)&feat[img * 32 + threadIdx.x], smax[threadIdx.x]);
}

// ---------------- head: adjacency + graph layer + MLP ----------------
__global__ __launch_bounds__(256) void k_head(const float* __restrict__ diffs,
    const float* __restrict__ feat, const float* __restrict__ gw,
    const float* __restrict__ gb, const float* __restrict__ w4,
    const float* __restrict__ b4, const float* __restrict__ w5,
    const float* __restrict__ b5, float* __restrict__ out)
{
  __shared__ float h66[4][66];
  __shared__ float hout[4][512];
  __shared__ float Am[4][4];
  __shared__ float pd[4][4][2];
  __shared__ float fs[4][32];
  const int b = blockIdx.x;
  const int tid = threadIdx.x;
  if (tid < 128) {
    int i = tid >> 5, c = tid & 31;
    fs[i][c] = feat[(b * 4 + i) * 32 + c];
  }
  if (tid == 0) {
    float lx[4], ly[4];
    #pragma unroll
    for (int a = 0; a < 4; ++a) {
      lx[a] = diffs[(b * 4 + a) * 2];
      ly[a] = diffs[(b * 4 + a) * 2 + 1];
    }
    #pragma unroll
    for (int i = 0; i < 4; ++i) {
      float A[4];
      float rs = 0.f;
      #pragma unroll
      for (int j = 0; j < 4; ++j) {
        float dx = lx[i] - lx[j], dy = ly[i] - ly[j];
        pd[i][j][0] = dx;
        pd[i][j][1] = dy;
        float n = sqrtf(dx * dx + dy * dy);
        A[j] = (n < 1.41421356237309504880f) ? 1.f : 0.f;
        rs += A[j];
      }
      float inv = 1.f / fmaxf(rs, 1e-6f);
      #pragma unroll
      for (int j = 0; j < 4; ++j)
        Am[i][j] = (i == j) ? 0.f : A[j] * inv;
    }
  }
  __syncthreads();
  if (tid < 128) {
    int i = tid >> 5, c = tid & 31;
    h66[i][c] = fs[i][c];
    float s = 0.f;
    #pragma unroll
    for (int j = 0; j < 4; ++j) s += Am[i][j] * fs[j][c];
    h66[i][32 + c] = s;
  } else if (tid < 136) {
    int q = tid - 128;
    int i = q >> 1, d = q & 1;
    float s = 0.f;
    #pragma unroll
    for (int j = 0; j < 4; ++j) s += Am[i][j] * pd[i][j][d];
    h66[i][64 + d] = s;
  }
  __syncthreads();
  #pragma unroll
  for (int r = 0; r < 2; ++r) {
    int o = tid + 256 * r;
    const float* wrow = &gw[o * 66];
    float a0 = gb[o], a1 = a0, a2 = a0, a3 = a0;
    for (int c = 0; c < 66; ++c) {
      float wv = wrow[c];
      a0 = fmaf(h66[0][c], wv, a0);
      a1 = fmaf(h66[1][c], wv, a1);
      a2 = fmaf(h66[2][c], wv, a2);
      a3 = fmaf(h66[3][c], wv, a3);
    }
    hout[0][o] = fmaxf(a0, 0.f);
    hout[1][o] = fmaxf(a1, 0.f);
    hout[2][o] = fmaxf(a2, 0.f);
    hout[3][o] = fmaxf(a3, 0.f);
  }
  __syncthreads();
  if (tid < 192) {
    int g = tid >> 4, l = tid & 15;
    int i = g / 3, k = g % 3;
    const float* wrow = (k < 2) ? &w4[k * 512] : w5;
    float s = 0.f;
    for (int o = l; o < 512; o += 16) s = fmaf(hout[i][o], wrow[o], s);
    #pragma unroll
    for (int d = 8; d >= 1; d >>= 1) s += __shfl_xor(s, d, 16);
    if (l == 0) {
      if (k < 2) out[(b * 4 + i) * 2 + k] = s + b4[k];
      else       out[1024 + b * 4 + i] = s + b5[0];
    }
  }
}

extern "C" void kernel_launch(void* const* d_in, const int* in_sizes, int n_in,
                              void* d_out, int out_size, void* d_ws, size_t ws_size,
                              hipStream_t stream) {
  const float* diffs  = (const float*)d_in[0];
  const float* states = (const float*)d_in[1];
  const float* w1 = (const float*)d_in[2];
  const float* b1 = (const float*)d_in[3];
  const float* w2 = (const float*)d_in[4];
  const float* b2 = (const float*)d_in[5];
  const float* gw = (const float*)d_in[6];
  const float* gb = (const float*)d_in[7];
  const float* w4 = (const float*)d_in[8];
  const float* b4 = (const float*)d_in[9];
  const float* w5 = (const float*)d_in[10];
  const float* b5 = (const float*)d_in[11];
  float* out = (float*)d_out;

  char* base = (char*)d_ws;
  float* wt1 = (float*)base;                       // 12288 B
  h2*    w2p = (h2*)(base + 12288);                // 25600 B -> ends 37888
  float* feat = (float*)(base + 37888);            // 65536 B -> ends 103424
  h2*    out1 = (h2*)(base + 103424);              // 512*8*57*57*4 B = 53.2 MB

  hipMemsetAsync(feat, 0, 512 * 32 * sizeof(float), stream);  // atomicMax identity
  k_repack<<<1, 256, 0, stream>>>(w1, w2, wt1, w2p);
  k_conv1<<<dim3(512, 15), 256, 0, stream>>>(states, wt1, b1, out1);
  k_conv2<<<dim3(512, 14), 256, 0, stream>>>(out1, w2p, b2, feat);
  k_head<<<128, 256, 0, stream>>>(diffs, feat, gw, gb, w4, b4, w5, b5, out);
}

// Round 3
// 211.736 us; speedup vs baseline: 11.6675x; 2.4629x over previous
//
#include <hip/hip_runtime.h>
#include <hip/hip_bf16.h>

#define H1 57   // 64-8+1
#define H2 53   // 57-5+1
#define XP 60   // padded x-stride of conv1 output (f16x4 units)

typedef _Float16 f16;
typedef _Float16 f16x4 __attribute__((ext_vector_type(4)));
typedef _Float16 f16x8 __attribute__((ext_vector_type(8)));
typedef float f32x4 __attribute__((ext_vector_type(4)));

// ---------------- weight repack ----------------
// wt1[c][kh][kw][oc16] fp32 for conv1.
// w2f: conv2 B-fragments in per-lane register order:
//   w2f[((tp*2+h)*64 + lane)*8 + j] = W2[oc=(lane&15)+16h][c=((lane>>4)<<2)+(j&3)]
//                                       [tap=2*tp+(j>>2)]   (tap==25 -> 0)
__global__ __launch_bounds__(256) void k_repack(const float* __restrict__ w1,
    const float* __restrict__ w2, float* __restrict__ wt1, f16* __restrict__ w2f)
{
  int t = threadIdx.x;
  for (int i = t; i < 3 * 8 * 8 * 16; i += 256) {
    int oc = i & 15;
    int r = i >> 4;                       // (c*8+kh)*8+kw
    wt1[i] = w1[oc * 192 + r];
  }
  for (int i = t; i < 13 * 2 * 64 * 8; i += 256) {
    int j = i & 7;
    int l = (i >> 3) & 63;
    int h = (i >> 9) & 1;
    int tp = i >> 10;
    int tap = 2 * tp + (j >> 2);
    int c = ((l >> 4) << 2) + (j & 3);
    int oc = (l & 15) + (h << 4);
    float v = (tap < 25) ? w2[((oc * 16 + c) * 5 + tap / 5) * 5 + tap % 5] : 0.f;
    w2f[i] = (f16)v;
  }
}

// ---------------- conv1: 3->16, 8x8, VALID, relu -> O1[img][g][y][x<60][c4] f16 ----
__global__ __launch_bounds__(256) void k_conv1(const float* __restrict__ in,
    const float* __restrict__ wt1, const float* __restrict__ b1,
    f16* __restrict__ O1)
{
  __shared__ float sIn[3][11][64];
  const int img = blockIdx.x;
  const int y0 = blockIdx.y * 4;
  const int reff = min(4, H1 - y0);
  for (int idx = threadIdx.x; idx < 3 * 11 * 64; idx += 256) {
    int x = idx & 63;
    int t = idx >> 6;
    int r = t % 11;
    int c = t / 11;
    int y = min(y0 + r, 63);
    sIn[c][r][x] = in[((img * 3 + c) * 64 + y) * 64 + x];
  }
  __syncthreads();
  const int w = __builtin_amdgcn_readfirstlane(threadIdx.x >> 6);
  const int lane = threadIdx.x & 63;
  const int x = min(lane, H1 - 1);
  float acc[16];
  #pragma unroll
  for (int o = 0; o < 16; ++o) acc[o] = b1[o];
  for (int c = 0; c < 3; ++c) {
    for (int kh = 0; kh < 8; ++kh) {
      const float* srow = &sIn[c][w + kh][0];
      const float* wp = &wt1[((c * 8 + kh) * 8) * 16];
      #pragma unroll
      for (int kw = 0; kw < 8; ++kw) {
        float xv = srow[x + kw];
        #pragma unroll
        for (int o = 0; o < 16; ++o)
          acc[o] = fmaf(xv, wp[kw * 16 + o], acc[o]);
      }
    }
  }
  if (w < reff && lane < H1) {
    const int y = y0 + w;
    #pragma unroll
    for (int g = 0; g < 4; ++g) {
      f16x4 v;
      #pragma unroll
      for (int q = 0; q < 4; ++q) v[q] = (f16)fmaxf(acc[g * 4 + q], 0.f);
      *(f16x4*)&O1[(((size_t)(img * 4 + g) * H1 + y) * XP + x) * 4] = v;
    }
  }
}

// ---------------- conv2 via MFMA implicit GEMM + fused global max ----------------
// grid (512, 7): y0 in {0,8,...,40,45}. block 256 = 4 waves.
// wave w: rows y0+2w, y0+2w+1; 4 x-tiles of 16 px; N = 32 oc (2 halves of 16).
__global__ __launch_bounds__(256) void k_conv2(const f16* __restrict__ O1,
    const f16* __restrict__ w2f, const float* __restrict__ b2,
    float* __restrict__ feat)
{
  __shared__ __align__(16) f16 sW[13 * 2 * 64 * 8];          // 26624 B
  __shared__ __align__(16) f16 sI[4 * 12 * XP * 4 + 64];     // 23168 B
  __shared__ unsigned smax[32];
  const int img = blockIdx.x;
  const int y0 = min((int)blockIdx.y * 8, 45);
  if (threadIdx.x < 32) smax[threadIdx.x] = 0u;
  // stage weights (1664 x 16B) and input strip (4 g-planes x 360 x 16B)
  for (int i = threadIdx.x; i < 1664; i += 256)
    ((float4*)sW)[i] = ((const float4*)w2f)[i];
  for (int i = threadIdx.x; i < 4 * 360; i += 256) {
    int g = i / 360, r = i % 360;
    ((float4*)sI)[g * 360 + r] =
        *(const float4*)(O1 + (((size_t)(img * 4 + g) * H1 + y0) * XP) * 4 + r * 8);
  }
  __syncthreads();

  const int lane = threadIdx.x & 63;
  const int wv = threadIdx.x >> 6;
  const int g = lane >> 4;       // 0..3 : k-group (A) / D-row group
  const int n16 = lane & 15;     // A row (pixel in tile) / D col (oc)

  f32x4 acc[2][4][2];
  #pragma unroll
  for (int r = 0; r < 2; ++r)
    #pragma unroll
    for (int xt = 0; xt < 4; ++xt)
      #pragma unroll
      for (int h = 0; h < 2; ++h)
        acc[r][xt][h] = (f32x4){0.f, 0.f, 0.f, 0.f};

  for (int tp = 0; tp < 13; ++tp) {
    f16x8 B0 = *(const f16x8*)&sW[((tp * 2 + 0) * 64 + lane) * 8];
    f16x8 B1 = *(const f16x8*)&sW[((tp * 2 + 1) * 64 + lane) * 8];
    const int t0 = 2 * tp;
    const int t1c = (t0 + 1 < 25) ? t0 + 1 : 0;   // tap 25 is zero-weight; clamp addr
    const int kh0 = t0 / 5, kw0 = t0 % 5;
    const int kh1 = t1c / 5, kw1 = t1c % 5;
    #pragma unroll
    for (int r = 0; r < 2; ++r) {
      const int yl = 2 * wv + r;
      const int row0 = (g * 12 + yl + kh0) * XP;
      const int row1 = (g * 12 + yl + kh1) * XP;
      #pragma unroll
      for (int xt = 0; xt < 4; ++xt) {
        const int px = xt * 16 + n16;
        f16x4 a0 = *(const f16x4*)&sI[(row0 + px + kw0) * 4];
        f16x4 a1 = *(const f16x4*)&sI[(row1 + px + kw1) * 4];
        union { struct { f16x4 lo, hi; } p; f16x8 v; } u;
        u.p.lo = a0; u.p.hi = a1;
        acc[r][xt][0] = __builtin_amdgcn_mfma_f32_16x16x32_f16(u.v, B0, acc[r][xt][0], 0, 0, 0);
        acc[r][xt][1] = __builtin_amdgcn_mfma_f32_16x16x32_f16(u.v, B1, acc[r][xt][1], 0, 0, 0);
      }
    }
  }

  // epilogue: bias + relu + mask invalid px + max over everything this lane holds
  const float bias0 = b2[n16];
  const float bias1 = b2[n16 + 16];
  float m0 = 0.f, m1 = 0.f;
  #pragma unroll
  for (int r = 0; r < 2; ++r)
    #pragma unroll
    for (int xt = 0; xt < 4; ++xt)
      #pragma unroll
      for (int q = 0; q < 4; ++q) {
        int px = xt * 16 + g * 4 + q;    // D row = pixel-in-row
        if (px < H2) {
          m0 = fmaxf(m0, acc[r][xt][0][q] + bias0);
          m1 = fmaxf(m1, acc[r][xt][1][q] + bias1);
        }
      }
  m0 = fmaxf(m0, 0.f);
  m1 = fmaxf(m1, 0.f);
  m0 = fmaxf(m0, __shfl_xor(m0, 16, 64));
  m0 = fmaxf(m0, __shfl_xor(m0, 32, 64));
  m1 = fmaxf(m1, __shfl_xor(m1, 16, 64));
  m1 = fmaxf(m1, __shfl_xor(m1, 32, 64));
  if (g == 0) {
    atomicMax(&smax[n16], __float_as_uint(m0));
    atomicMax(&smax[n16 + 16], __float_as_uint(m1));
  }
  __syncthreads();
  if (threadIdx.x < 32)
    atomicMax((unsigned*)&feat[img * 32 + threadIdx.x], smax[threadIdx.x]);
}

// ---------------- head: adjacency + graph layer + MLP ----------------
__global__ __launch_bounds__(256) void k_head(const float* __restrict__ diffs,
    const float* __restrict__ feat, const float* __restrict__ gw,
    const float* __restrict__ gb, const float* __restrict__ w4,
    const float* __restrict__ b4, const float* __restrict__ w5,
    const float* __restrict__ b5, float* __restrict__ out)
{
  __shared__ float h66[4][66];
  __shared__ float hout[4][512];
  __shared__ float Am[4][4];
  __shared__ float pd[4][4][2];
  __shared__ float fs[4][32];
  const int b = blockIdx.x;
  const int tid = threadIdx.x;
  if (tid < 128) {
    int i = tid >> 5, c = tid & 31;
    fs[i][c] = feat[(b * 4 + i) * 32 + c];
  }
  if (tid == 0) {
    float lx[4], ly[4];
    #pragma unroll
    for (int a = 0; a < 4; ++a) {
      lx[a] = diffs[(b * 4 + a) * 2];
      ly[a] = diffs[(b * 4 + a) * 2 + 1];
    }
    #pragma unroll
    for (int i = 0; i < 4; ++i) {
      float A[4];
      float rs = 0.f;
      #pragma unroll
      for (int j = 0; j < 4; ++j) {
        float dx = lx[i] - lx[j], dy = ly[i] - ly[j];
        pd[i][j][0] = dx;
        pd[i][j][1] = dy;
        float n = sqrtf(dx * dx + dy * dy);
        A[j] = (n < 1.41421356237309504880f) ? 1.f : 0.f;
        rs += A[j];
      }
      float inv = 1.f / fmaxf(rs, 1e-6f);
      #pragma unroll
      for (int j = 0; j < 4; ++j)
        Am[i][j] = (i == j) ? 0.f : A[j] * inv;
    }
  }
  __syncthreads();
  if (tid < 128) {
    int i = tid >> 5, c = tid & 31;
    h66[i][c] = fs[i][c];
    float s = 0.f;
    #pragma unroll
    for (int j = 0; j < 4; ++j) s += Am[i][j] * fs[j][c];
    h66[i][32 + c] = s;
  } else if (tid < 136) {
    int q = tid - 128;
    int i = q >> 1, d = q & 1;
    float s = 0.f;
    #pragma unroll
    for (int j = 0; j < 4; ++j) s += Am[i][j] * pd[i][j][d];
    h66[i][64 + d] = s;
  }
  __syncthreads();
  #pragma unroll
  for (int r = 0; r < 2; ++r) {
    int o = tid + 256 * r;
    const float* wrow = &gw[o * 66];
    float a0 = gb[o], a1 = a0, a2 = a0, a3 = a0;
    for (int c = 0; c < 66; ++c) {
      float wv = wrow[c];
      a0 = fmaf(h66[0][c], wv, a0);
      a1 = fmaf(h66[1][c], wv, a1);
      a2 = fmaf(h66[2][c], wv, a2);
      a3 = fmaf(h66[3][c], wv, a3);
    }
    hout[0][o] = fmaxf(a0, 0.f);
    hout[1][o] = fmaxf(a1, 0.f);
    hout[2][o] = fmaxf(a2, 0.f);
    hout[3][o] = fmaxf(a3, 0.f);
  }
  __syncthreads();
  if (tid < 192) {
    int gq = tid >> 4, l = tid & 15;
    int i = gq / 3, k = gq % 3;
    const float* wrow = (k < 2) ? &w4[k * 512] : w5;
    float s = 0.f;
    for (int o = l; o < 512; o += 16) s = fmaf(hout[i][o], wrow[o], s);
    #pragma unroll
    for (int d = 8; d >= 1; d >>= 1) s += __shfl_xor(s, d, 16);
    if (l == 0) {
      if (k < 2) out[(b * 4 + i) * 2 + k] = s + b4[k];
      else       out[1024 + b * 4 + i] = s + b5[0];
    }
  }
}

extern "C" void kernel_launch(void* const* d_in, const int* in_sizes, int n_in,
                              void* d_out, int out_size, void* d_ws, size_t ws_size,
                              hipStream_t stream) {
  const float* diffs  = (const float*)d_in[0];
  const float* states = (const float*)d_in[1];
  const float* w1 = (const float*)d_in[2];
  const float* b1 = (const float*)d_in[3];
  const float* w2 = (const float*)d_in[4];
  const float* b2 = (const float*)d_in[5];
  const float* gw = (const float*)d_in[6];
  const float* gb = (const float*)d_in[7];
  const float* w4 = (const float*)d_in[8];
  const float* b4 = (const float*)d_in[9];
  const float* w5 = (const float*)d_in[10];
  const float* b5 = (const float*)d_in[11];
  float* out = (float*)d_out;

  char* base = (char*)d_ws;
  float* wt1 = (float*)base;                  // 12288 B
  f16*   w2f = (f16*)(base + 12288);          // 26624 B -> 38912
  float* feat = (float*)(base + 38912);       // 65536 B -> 104448
  f16*   O1  = (f16*)(base + 104448);         // 512*4*57*60*4 f16 = 56.0 MB

  hipMemsetAsync(feat, 0, 512 * 32 * sizeof(float), stream);  // atomicMax identity
  k_repack<<<1, 256, 0, stream>>>(w1, w2, wt1, w2f);
  k_conv1<<<dim3(512, 15), 256, 0, stream>>>(states, wt1, b1, O1);
  k_conv2<<<dim3(512, 7), 256, 0, stream>>>(O1, w2f, b2, feat);
  k_head<<<128, 256, 0, stream>>>(diffs, feat, gw, gb, w4, b4, w5, b5, out);
}

// Round 4
// 120.683 us; speedup vs baseline: 20.4704x; 1.7545x over previous
//
#include <hip/hip_runtime.h>
#include <hip/hip_bf16.h>

#define H1 57   // 64-8+1
#define H2 53   // 57-5+1
#define XP 60   // padded x-stride of conv1 output (f16x4 units)

typedef _Float16 f16;
typedef _Float16 f16x4 __attribute__((ext_vector_type(4)));
typedef _Float16 f16x8 __attribute__((ext_vector_type(8)));
typedef float f32x4 __attribute__((ext_vector_type(4)));

// ---------------- weight repack ----------------
// w1f: conv1 B-fragments: w1f[(tp*64+l)*8+j] = W1[oc=l&15][c=j&3][kh=tp][kw=4*(j>>2)+(l>>4)]
//      (c==3 -> 0). K = 4ch x 64 taps = 256 = 8 steps of 32.
// w2f: conv2 B-fragments (unchanged from round 3):
//   w2f[((tp*2+h)*64+l)*8+j] = W2[oc=(l&15)+16h][c=((l>>4)<<2)+(j&3)][tap=2tp+(j>>2)] (tap 25 -> 0)
__global__ __launch_bounds__(256) void k_repack(const float* __restrict__ w1,
    const float* __restrict__ w2, f16* __restrict__ w1f, f16* __restrict__ w2f)
{
  int t = threadIdx.x;
  for (int i = t; i < 8 * 64 * 8; i += 256) {
    int j = i & 7;
    int l = (i >> 3) & 63;
    int tp = i >> 9;
    int c = j & 3;
    int kh = tp;
    int kw = 4 * (j >> 2) + (l >> 4);
    int oc = l & 15;
    float v = (c < 3) ? w1[((oc * 3 + c) * 8 + kh) * 8 + kw] : 0.f;
    w1f[i] = (f16)v;
  }
  for (int i = t; i < 13 * 2 * 64 * 8; i += 256) {
    int j = i & 7;
    int l = (i >> 3) & 63;
    int h = (i >> 9) & 1;
    int tp = i >> 10;
    int tap = 2 * tp + (j >> 2);
    int c = ((l >> 4) << 2) + (j & 3);
    int oc = (l & 15) + (h << 4);
    float v = (tap < 25) ? w2[((oc * 16 + c) * 5 + tap / 5) * 5 + tap % 5] : 0.f;
    w2f[i] = (f16)v;
  }
}

// ---------------- conv1 via MFMA implicit GEMM ----------------
// grid (512, 8): y0 = min(8*by, 49). block 256 = 4 waves.
// wave w: rows y0+2w, y0+2w+1; 4 x-tiles of 16 px; N = 16 oc.
__global__ __launch_bounds__(256) void k_conv1(const float* __restrict__ in,
    const f16* __restrict__ w1f, const float* __restrict__ b1,
    f16* __restrict__ O1)
{
  __shared__ __align__(16) f16 sIn[15][72][4];   // 8640 B, c4 channels-last
  __shared__ __align__(16) f16 sW[8 * 64 * 8];   // 8192 B
  __shared__ __align__(16) f16 sT[4][64][20];    // 10240 B, per-wave transpose
  const int img = blockIdx.x;
  const int y0 = min((int)blockIdx.y * 8, 49);
  // stage weights: 512 x 16B
  for (int i = threadIdx.x; i < 512; i += 256)
    ((float4*)sW)[i] = ((const float4*)w1f)[i];
  // stage input strip: 15 rows x 64 x, 3 ch fp32 -> f16 c4
  for (int i = threadIdx.x; i < 15 * 16; i += 256) {
    int y = i >> 4, xq = i & 15;
    const float* p0 = &in[(((size_t)img * 3 + 0) * 64 + (y0 + y)) * 64 + xq * 4];
    float4 v0 = *(const float4*)p0;
    float4 v1 = *(const float4*)(p0 + 4096);
    float4 v2 = *(const float4*)(p0 + 8192);
    float c0[4] = {v0.x, v0.y, v0.z, v0.w};
    float c1[4] = {v1.x, v1.y, v1.z, v1.w};
    float c2[4] = {v2.x, v2.y, v2.z, v2.w};
    #pragma unroll
    for (int q = 0; q < 4; ++q) {
      f16x4 t = {(f16)c0[q], (f16)c1[q], (f16)c2[q], (f16)0.f};
      *(f16x4*)&sIn[y][xq * 4 + q][0] = t;
    }
  }
  // zero x-pad columns 64..71 (read by px>=57 lanes, results masked but keep finite)
  for (int i = threadIdx.x; i < 15 * 8; i += 256) {
    int y = i >> 3, xi = i & 7;
    *(f16x4*)&sIn[y][64 + xi][0] = (f16x4){(f16)0.f, (f16)0.f, (f16)0.f, (f16)0.f};
  }
  __syncthreads();

  const int lane = threadIdx.x & 63;
  const int wv = threadIdx.x >> 6;
  const int g = lane >> 4;       // k-group (A) / D-row group
  const int n16 = lane & 15;     // A row (pixel) / D col (oc)

  f16x8 Bf[8];
  #pragma unroll
  for (int tp = 0; tp < 8; ++tp)
    Bf[tp] = *(const f16x8*)&sW[(tp * 64 + lane) * 8];

  const float bias = b1[n16];
  f32x4 acc[2][4];
  #pragma unroll
  for (int r = 0; r < 2; ++r)
    #pragma unroll
    for (int xt = 0; xt < 4; ++xt)
      acc[r][xt] = (f32x4){bias, bias, bias, bias};

  #pragma unroll
  for (int tp = 0; tp < 8; ++tp) {        // kh = tp
    #pragma unroll
    for (int r = 0; r < 2; ++r) {
      const int row = 2 * wv + r + tp;
      #pragma unroll
      for (int xt = 0; xt < 4; ++xt) {
        const int px = xt * 16 + n16;
        f16x4 a0 = *(const f16x4*)&sIn[row][px + g][0];       // kw = g
        f16x4 a1 = *(const f16x4*)&sIn[row][px + 4 + g][0];   // kw = 4+g
        union { struct { f16x4 lo, hi; } p; f16x8 v; } u;
        u.p.lo = a0; u.p.hi = a1;
        acc[r][xt] = __builtin_amdgcn_mfma_f32_16x16x32_f16(u.v, Bf[tp], acc[r][xt], 0, 0, 0);
      }
    }
  }

  // epilogue: relu, per-wave LDS transpose (oc-major -> c4), coalesced store
  #pragma unroll
  for (int r = 0; r < 2; ++r) {
    #pragma unroll
    for (int xt = 0; xt < 4; ++xt)
      #pragma unroll
      for (int q = 0; q < 4; ++q)
        sT[wv][xt * 16 + g * 4 + q][n16] = (f16)fmaxf(acc[r][xt][q], 0.f);
    const int yy = y0 + 2 * wv + r;
    if (lane < H1) {
      #pragma unroll
      for (int go = 0; go < 4; ++go) {
        f16x4 v = *(const f16x4*)&sT[wv][lane][go * 4];
        *(f16x4*)&O1[(((size_t)(img * 4 + go) * H1 + yy) * XP + lane) * 4] = v;
      }
    }
  }
}

// ---------------- conv2 via MFMA implicit GEMM + fused global max ----------------
// grid (512, 7): y0 in {0,8,...,40,45}. block 256 = 4 waves.
__global__ __launch_bounds__(256) void k_conv2(const f16* __restrict__ O1,
    const f16* __restrict__ w2f, const float* __restrict__ b2,
    float* __restrict__ feat)
{
  __shared__ __align__(16) f16 sW[13 * 2 * 64 * 8];          // 26624 B
  __shared__ __align__(16) f16 sI[4 * 12 * XP * 4 + 64];     // 23168 B
  __shared__ unsigned smax[32];
  const int img = blockIdx.x;
  const int y0 = min((int)blockIdx.y * 8, 45);
  if (threadIdx.x < 32) smax[threadIdx.x] = 0u;
  for (int i = threadIdx.x; i < 1664; i += 256)
    ((float4*)sW)[i] = ((const float4*)w2f)[i];
  for (int i = threadIdx.x; i < 4 * 360; i += 256) {
    int g = i / 360, r = i % 360;
    ((float4*)sI)[g * 360 + r] =
        *(const float4*)(O1 + (((size_t)(img * 4 + g) * H1 + y0) * XP) * 4 + r * 8);
  }
  __syncthreads();

  const int lane = threadIdx.x & 63;
  const int wv = threadIdx.x >> 6;
  const int g = lane >> 4;
  const int n16 = lane & 15;

  f32x4 acc[2][4][2];
  #pragma unroll
  for (int r = 0; r < 2; ++r)
    #pragma unroll
    for (int xt = 0; xt < 4; ++xt)
      #pragma unroll
      for (int h = 0; h < 2; ++h)
        acc[r][xt][h] = (f32x4){0.f, 0.f, 0.f, 0.f};

  for (int tp = 0; tp < 13; ++tp) {
    f16x8 B0 = *(const f16x8*)&sW[((tp * 2 + 0) * 64 + lane) * 8];
    f16x8 B1 = *(const f16x8*)&sW[((tp * 2 + 1) * 64 + lane) * 8];
    const int t0 = 2 * tp;
    const int t1c = (t0 + 1 < 25) ? t0 + 1 : 0;   // tap 25 is zero-weight; clamp addr
    const int kh0 = t0 / 5, kw0 = t0 % 5;
    const int kh1 = t1c / 5, kw1 = t1c % 5;
    #pragma unroll
    for (int r = 0; r < 2; ++r) {
      const int yl = 2 * wv + r;
      const int row0 = (g * 12 + yl + kh0) * XP;
      const int row1 = (g * 12 + yl + kh1) * XP;
      #pragma unroll
      for (int xt = 0; xt < 4; ++xt) {
        const int px = xt * 16 + n16;
        f16x4 a0 = *(const f16x4*)&sI[(row0 + px + kw0) * 4];
        f16x4 a1 = *(const f16x4*)&sI[(row1 + px + kw1) * 4];
        union { struct { f16x4 lo, hi; } p; f16x8 v; } u;
        u.p.lo = a0; u.p.hi = a1;
        acc[r][xt][0] = __builtin_amdgcn_mfma_f32_16x16x32_f16(u.v, B0, acc[r][xt][0], 0, 0, 0);
        acc[r][xt][1] = __builtin_amdgcn_mfma_f32_16x16x32_f16(u.v, B1, acc[r][xt][1], 0, 0, 0);
      }
    }
  }

  const float bias0 = b2[n16];
  const float bias1 = b2[n16 + 16];
  float m0 = 0.f, m1 = 0.f;
  #pragma unroll
  for (int r = 0; r < 2; ++r)
    #pragma unroll
    for (int xt = 0; xt < 4; ++xt)
      #pragma unroll
      for (int q = 0; q < 4; ++q) {
        int px = xt * 16 + g * 4 + q;
        if (px < H2) {
          m0 = fmaxf(m0, acc[r][xt][0][q] + bias0);
          m1 = fmaxf(m1, acc[r][xt][1][q] + bias1);
        }
      }
  m0 = fmaxf(m0, 0.f);
  m1 = fmaxf(m1, 0.f);
  m0 = fmaxf(m0, __shfl_xor(m0, 16, 64));
  m0 = fmaxf(m0, __shfl_xor(m0, 32, 64));
  m1 = fmaxf(m1, __shfl_xor(m1, 16, 64));
  m1 = fmaxf(m1, __shfl_xor(m1, 32, 64));
  if (g == 0) {
    atomicMax(&smax[n16], __float_as_uint(m0));
    atomicMax(&smax[n16 + 16], __float_as_uint(m1));
  }
  __syncthreads();
  if (threadIdx.x < 32)
    atomicMax((unsigned*)&feat[img * 32 + threadIdx.x], smax[threadIdx.x]);
}

// ---------------- head: adjacency + graph layer + MLP ----------------
__global__ __launch_bounds__(256) void k_head(const float* __restrict__ diffs,
    const float* __restrict__ feat, const float* __restrict__ gw,
    const float* __restrict__ gb, const float* __restrict__ w4,
    const float* __restrict__ b4, const float* __restrict__ w5,
    const float* __restrict__ b5, float* __restrict__ out)
{
  __shared__ float h66[4][66];
  __shared__ float hout[4][512];
  __shared__ float Am[4][4];
  __shared__ float pd[4][4][2];
  __shared__ float fs[4][32];
  const int b = blockIdx.x;
  const int tid = threadIdx.x;
  if (tid < 128) {
    int i = tid >> 5, c = tid & 31;
    fs[i][c] = feat[(b * 4 + i) * 32 + c];
  }
  if (tid == 0) {
    float lx[4], ly[4];
    #pragma unroll
    for (int a = 0; a < 4; ++a) {
      lx[a] = diffs[(b * 4 + a) * 2];
      ly[a] = diffs[(b * 4 + a) * 2 + 1];
    }
    #pragma unroll
    for (int i = 0; i < 4; ++i) {
      float A[4];
      float rs = 0.f;
      #pragma unroll
      for (int j = 0; j < 4; ++j) {
        float dx = lx[i] - lx[j], dy = ly[i] - ly[j];
        pd[i][j][0] = dx;
        pd[i][j][1] = dy;
        float n = sqrtf(dx * dx + dy * dy);
        A[j] = (n < 1.41421356237309504880f) ? 1.f : 0.f;
        rs += A[j];
      }
      float inv = 1.f / fmaxf(rs, 1e-6f);
      #pragma unroll
      for (int j = 0; j < 4; ++j)
        Am[i][j] = (i == j) ? 0.f : A[j] * inv;
    }
  }
  __syncthreads();
  if (tid < 128) {
    int i = tid >> 5, c = tid & 31;
    h66[i][c] = fs[i][c];
    float s = 0.f;
    #pragma unroll
    for (int j = 0; j < 4; ++j) s += Am[i][j] * fs[j][c];
    h66[i][32 + c] = s;
  } else if (tid < 136) {
    int q = tid - 128;
    int i = q >> 1, d = q & 1;
    float s = 0.f;
    #pragma unroll
    for (int j = 0; j < 4; ++j) s += Am[i][j] * pd[i][j][d];
    h66[i][64 + d] = s;
  }
  __syncthreads();
  #pragma unroll
  for (int r = 0; r < 2; ++r) {
    int o = tid + 256 * r;
    const float* wrow = &gw[o * 66];
    float a0 = gb[o], a1 = a0, a2 = a0, a3 = a0;
    for (int c = 0; c < 66; ++c) {
      float wv = wrow[c];
      a0 = fmaf(h66[0][c], wv, a0);
      a1 = fmaf(h66[1][c], wv, a1);
      a2 = fmaf(h66[2][c], wv, a2);
      a3 = fmaf(h66[3][c], wv, a3);
    }
    hout[0][o] = fmaxf(a0, 0.f);
    hout[1][o] = fmaxf(a1, 0.f);
    hout[2][o] = fmaxf(a2, 0.f);
    hout[3][o] = fmaxf(a3, 0.f);
  }
  __syncthreads();
  if (tid < 192) {
    int gq = tid >> 4, l = tid & 15;
    int i = gq / 3, k = gq % 3;
    const float* wrow = (k < 2) ? &w4[k * 512] : w5;
    float s = 0.f;
    for (int o = l; o < 512; o += 16) s = fmaf(hout[i][o], wrow[o], s);
    #pragma unroll
    for (int d = 8; d >= 1; d >>= 1) s += __shfl_xor(s, d, 16);
    if (l == 0) {
      if (k < 2) out[(b * 4 + i) * 2 + k] = s + b4[k];
      else       out[1024 + b * 4 + i] = s + b5[0];
    }
  }
}

extern "C" void kernel_launch(void* const* d_in, const int* in_sizes, int n_in,
                              void* d_out, int out_size, void* d_ws, size_t ws_size,
                              hipStream_t stream) {
  const float* diffs  = (const float*)d_in[0];
  const float* states = (const float*)d_in[1];
  const float* w1 = (const float*)d_in[2];
  const float* b1 = (const float*)d_in[3];
  const float* w2 = (const float*)d_in[4];
  const float* b2 = (const float*)d_in[5];
  const float* gw = (const float*)d_in[6];
  const float* gb = (const float*)d_in[7];
  const float* w4 = (const float*)d_in[8];
  const float* b4 = (const float*)d_in[9];
  const float* w5 = (const float*)d_in[10];
  const float* b5 = (const float*)d_in[11];
  float* out = (float*)d_out;

  char* base = (char*)d_ws;
  f16*   w1f = (f16*)base;                    // 8192 B
  f16*   w2f = (f16*)(base + 8192);           // 26624 B -> 34816
  float* feat = (float*)(base + 34816);       // 65536 B -> 100352
  f16*   O1  = (f16*)(base + 100352);         // 512*4*57*60*4 f16 = 56.0 MB

  hipMemsetAsync(feat, 0, 512 * 32 * sizeof(float), stream);  // atomicMax identity
  k_repack<<<1, 256, 0, stream>>>(w1, w2, w1f, w2f);
  k_conv1<<<dim3(512, 8), 256, 0, stream>>>(states, w1f, b1, O1);
  k_conv2<<<dim3(512, 7), 256, 0, stream>>>(O1, w2f, b2, feat);
  k_head<<<128, 256, 0, stream>>>(diffs, feat, gw, gb, w4, b4, w5, b5, out);
}